// Round 16
// baseline (4060.728 us; speedup 1.0000x reference)
//
#include <hip/hip_runtime.h>
#include <hip/hip_cooperative_groups.h>

namespace cg = cooperative_groups;

#define BB 8
#define TT 16
#define HH 256
#define WW 256
#define HW (HH*WW)            // 65536
#define NPT (BB*HW)           // 524288 points
#define NTH (NPT/2)           // 262144 threads, 2 points each
#define EMPTY_FLOOR 0.012f

// ws layout: pairs[2 bufs][NPT][2]f32 = 8 MB (proven footprint).
// pairs[buf][b*HW+cell] = {acc, wacc} — adjacent so the 2 atomics/corner
// share a cache line. State (X,Y,R) lives in REGISTERS for all 16 steps.
// One cooperative kernel, one grid.sync per step (double-buffered pairs).
// Arithmetic: VERBATIM R15 (A-init f32 bits; f64 step math, f32 state
// rounding; R6-f32 defused splat; empty-cell floor) — do not touch.

__device__ __forceinline__ float fmul_sr(float a, float b) {
    float r = a * b;
    __asm__("" : "+v"(r));
    return r;
}

__global__ __launch_bounds__(256, 4)
void k_all(const float* __restrict__ x, const float* __restrict__ dec,
           float* __restrict__ out, float* __restrict__ pairs) {
#pragma clang fp contract(off)
    cg::grid_group grid = cg::this_grid();
    int tid = blockIdx.x * blockDim.x + threadIdx.x;   // 0..NTH-1

    // --- zero my slots in both pair buffers ---
    #pragma unroll
    for (int q = 0; q < 2; ++q) {
        int id = tid + q * NTH;
        pairs[2*id]             = 0.0f;
        pairs[2*id + 1]         = 0.0f;
        pairs[2*(NPT + id)]     = 0.0f;
        pairs[2*(NPT + id) + 1] = 0.0f;
    }

    // --- init state in registers (A-init f32 bits, proven) ---
    float Xs[2], Ys[2], Rs[2];
    #pragma unroll
    for (int q = 0; q < 2; ++q) {
        int id = tid + q * NTH;
        int b = id >> 16, p = id & (HW - 1);
        int px = p & (WW - 1), py = p >> 8;
        Xs[q] = (float)px * (1.0f / 255.0f);
        Ys[q] = (float)py * (1.0f / 255.0f);
        Rs[q] = x[(size_t)(b * TT + (TT - 1)) * HW + p];
    }

    grid.sync();   // pair buffers zeroed grid-wide

    for (int t = 0; t < TT; ++t) {
        float* pb = pairs + (size_t)(t & 1) * (2 * (size_t)NPT);

        #pragma unroll
        for (int q = 0; q < 2; ++q) {
            int id = tid + q * NTH;
            int b = id >> 16;
            const float* U = dec + (size_t)((b * TT + t) * 3) * HW;
            const float* V = U + HW;
            const float* C = U + 2 * HW;

            // ---- R15-verbatim: f64 gather/update from f32 state ----
            double X = (double)Xs[q], Y = (double)Ys[q], R = (double)Rs[q];
            double ix = X * 256.0 - 0.5;
            double iy = Y * 256.0 - 0.5;
            double x0 = floor(ix);
            double y0 = floor(iy);

            double gU = 0.0, gV = 0.0, gC = 0.0;
            #pragma unroll
            for (int k = 0; k < 4; ++k) {
                double dxf = (double)(k & 1), dyf = (double)(k >> 1);
                double xc = x0 + dxf, yc = y0 + dyf;
                double w = (1.0 - fabs(ix - xc)) * (1.0 - fabs(iy - yc));
                bool valid = (xc >= 0.0) && (xc < 256.0) && (yc >= 0.0) && (yc < 256.0);
                double wv = valid ? w : 0.0;
                int xi = (int)fmin(fmax(xc, 0.0), 255.0);
                int yi = (int)fmin(fmax(yc, 0.0), 255.0);
                int ii = yi * WW + xi;
                double uT = (((double)U[ii] - 0.5) * 5.0) / 256.0;
                double vT = (((double)V[ii] - 0.5) * 5.0) / 256.0;
                double cT = (double)C[ii];
                gU = gU + uT * wv;
                gV = gV + vT * wv;
                gC = gC + cT * wv;
            }

            double nXd = X + gU; nXd = fmin(fmax(nXd, 0.0), 1.0);
            double nYd = Y + gV; nYd = fmin(fmax(nYd, 0.0), 1.0);
            double nRd = R * gC; nRd = fmin(fmax(nRd, 0.0), 1.0);
            float nX = (float)nXd;
            float nY = (float)nYd;
            float nR = (float)nRd;
            Xs[q] = nX; Ys[q] = nY; Rs[q] = nR;

            // ---- R15-verbatim splat (f32, defused), paired targets ----
            float sx = fmul_sr(nX, 255.0f);
            float sy = fmul_sr(nY, 255.0f);
            float sx0 = floorf(sx);
            float sy0 = floorf(sy);

            float* pbB = pb + 2 * (size_t)(b * HW);
            #pragma unroll
            for (int k = 0; k < 4; ++k) {
                float dxf = (float)(k & 1), dyf = (float)(k >> 1);
                float xc = sx0 + dxf, yc = sy0 + dyf;
                float w = fmul_sr(1.0f - fabsf(sx - xc), 1.0f - fabsf(sy - yc));
                bool valid = (xc >= 0.0f) && (xc <= 255.0f) && (yc >= 0.0f) && (yc <= 255.0f);
                float wv = valid ? w : 0.0f;
                if (wv != 0.0f) {
                    int xi = (int)fminf(fmaxf(xc, 0.0f), 255.0f);
                    int yi = (int)fminf(fmaxf(yc, 0.0f), 255.0f);
                    int ii = yi * WW + xi;
                    atomicAdd(pbB + 2*ii,     fmul_sr(nR, wv));
                    atomicAdd(pbB + 2*ii + 1, wv);
                }
            }
        }

        grid.sync();   // all atomics for step t landed

        // ---- fin: normalize slice t, rezero this buffer ----
        #pragma unroll
        for (int q = 0; q < 2; ++q) {
            int id = tid + q * NTH;
            int b = id >> 16, p = id & (HW - 1);
            float a = pb[2*id];
            float w = pb[2*id + 1];
            out[(size_t)(b * TT + t) * HW + p] =
                (w == 0.0f) ? EMPTY_FLOOR : a / fmaxf(w, 1e-8f);
            pb[2*id]     = 0.0f;
            pb[2*id + 1] = 0.0f;
        }
        // no second sync needed: next step uses the OTHER buffer; this
        // buffer's rezero is ordered before its reuse by next step's sync.
    }
}

extern "C" void kernel_launch(void* const* d_in, const int* in_sizes, int n_in,
                              void* d_out, int out_size, void* d_ws, size_t ws_size,
                              hipStream_t stream) {
    const float* x   = (const float*)d_in[0];
    const float* dec = (const float*)d_in[1];
    float* out   = (float*)d_out;
    float* pairs = (float*)d_ws;          // 8 MB

    void* args[] = { (void*)&x, (void*)&dec, (void*)&out, (void*)&pairs };
    hipLaunchCooperativeKernel((void*)k_all, dim3(NTH / 256), dim3(256),
                               args, 0, stream);
}

// Round 17
// 2080.916 us; speedup vs baseline: 1.9514x; 1.9514x over previous
//
#include <hip/hip_runtime.h>

#define BB 8
#define TT 16
#define HH 256
#define WW 256
#define HW (HH*WW)            // 65536
#define NPT (BB*HW)           // 524288 points
#define NOUT (BB*TT*HW)       // 8388608 output elems
#define EMPTY_FLOOR 0.012f

// ws layout: state float4[NPT] (X,Y,R,-) = 8 MB | wacc[2][NPT] f32 = 4 MB.
// Total 12 MB (<= 14 MB proven in R12). acc accumulates directly in d_out.
// Arithmetic VERBATIM R15 (A-init f32 bits; f64 step math, f32 state
// rounding; R6-f32 defused splat; empty-cell floor). DO NOT TOUCH.
// Structure: k_init; 16x k_fused(t) = { fin(t-1) ; step(t) }; k_finlast.
// wacc double-buffered: step(t) -> buf[t&1]; fin(t) reads+rezeros buf[t&1]
// inside k_fused(t+1). Kernel boundaries provide all needed ordering.

__device__ __forceinline__ float fmul_sr(float a, float b) {
    float r = a * b;
    __asm__("" : "+v"(r));
    return r;
}

__global__ void k_init(const float* __restrict__ x, float* __restrict__ out,
                       float4* __restrict__ st, float* __restrict__ wacc) {
    int idx = blockIdx.x * blockDim.x + threadIdx.x;
    if (idx < NOUT) out[idx] = 0.0f;
    if (idx < 2 * NPT) wacc[idx] = 0.0f;
    if (idx < NPT) {
        int b  = idx >> 16;
        int p  = idx & (HW - 1);
        int px = p & (WW - 1);
        int py = p >> 8;
        float4 s;
        s.x = (float)px * (1.0f / 255.0f);   // A-init bits (proven basin)
        s.y = (float)py * (1.0f / 255.0f);
        s.z = x[(size_t)(b * TT + (TT - 1)) * HW + p];
        s.w = 0.0f;
        st[idx] = s;
    }
}

__device__ __forceinline__ void do_fin(float* __restrict__ out,
                                       float* __restrict__ waccbuf,
                                       int idx, int t) {
    int b = idx >> 16;
    int p = idx & (HW - 1);
    size_t o = (size_t)(b * TT + t) * HW + p;
    float wsum = waccbuf[idx];
    out[o] = (wsum == 0.0f) ? EMPTY_FLOOR : out[o] / fmaxf(wsum, 1e-8f);
    waccbuf[idx] = 0.0f;
}

__global__ void k_fused(const float* __restrict__ dec, float* __restrict__ out,
                        float4* __restrict__ st, float* __restrict__ wacc,
                        int t) {
#pragma clang fp contract(off)
    int idx = blockIdx.x * blockDim.x + threadIdx.x;
    if (idx >= NPT) return;

    // ---- fin(t-1): normalize previous slice, rezero its wacc buffer ----
    if (t > 0) do_fin(out, wacc + (size_t)((t - 1) & 1) * NPT, idx, t - 1);

    int b = idx >> 16;
    const float* U = dec + (size_t)((b * TT + t) * 3) * HW;
    const float* V = U + HW;
    const float* C = U + 2 * HW;

    float4 s = st[idx];

    // ---- R15-verbatim: f64 gather/update from f32 state ----
    double X = (double)s.x, Y = (double)s.y, R = (double)s.z;
    double ix = X * 256.0 - 0.5;
    double iy = Y * 256.0 - 0.5;
    double x0 = floor(ix);
    double y0 = floor(iy);

    double gU = 0.0, gV = 0.0, gC = 0.0;
    #pragma unroll
    for (int k = 0; k < 4; ++k) {
        double dxf = (double)(k & 1), dyf = (double)(k >> 1);
        double xc = x0 + dxf, yc = y0 + dyf;
        double w = (1.0 - fabs(ix - xc)) * (1.0 - fabs(iy - yc));
        bool valid = (xc >= 0.0) && (xc < 256.0) && (yc >= 0.0) && (yc < 256.0);
        double wv = valid ? w : 0.0;
        int xi = (int)fmin(fmax(xc, 0.0), 255.0);
        int yi = (int)fmin(fmax(yc, 0.0), 255.0);
        int ii = yi * WW + xi;
        double uT = (((double)U[ii] - 0.5) * 5.0) / 256.0;
        double vT = (((double)V[ii] - 0.5) * 5.0) / 256.0;
        double cT = (double)C[ii];
        gU = gU + uT * wv;
        gV = gV + vT * wv;
        gC = gC + cT * wv;
    }

    double nXd = X + gU; nXd = fmin(fmax(nXd, 0.0), 1.0);
    double nYd = Y + gV; nYd = fmin(fmax(nYd, 0.0), 1.0);
    double nRd = R * gC; nRd = fmin(fmax(nRd, 0.0), 1.0);
    float nX = (float)nXd;
    float nY = (float)nYd;
    float nR = (float)nRd;
    s.x = nX; s.y = nY; s.z = nR;
    st[idx] = s;

    // ---- R15-verbatim splat (f32, defused); acc->out, wacc->buf[t&1] ----
    float sx = fmul_sr(nX, 255.0f);
    float sy = fmul_sr(nY, 255.0f);
    float sx0 = floorf(sx);
    float sy0 = floorf(sy);

    float* ab = out + (size_t)(b * TT + t) * HW;
    float* wb = wacc + (size_t)(t & 1) * NPT + (size_t)b * HW;

    #pragma unroll
    for (int k = 0; k < 4; ++k) {
        float dxf = (float)(k & 1), dyf = (float)(k >> 1);
        float xc = sx0 + dxf, yc = sy0 + dyf;
        float w = fmul_sr(1.0f - fabsf(sx - xc), 1.0f - fabsf(sy - yc));
        bool valid = (xc >= 0.0f) && (xc <= 255.0f) && (yc >= 0.0f) && (yc <= 255.0f);
        float wv = valid ? w : 0.0f;
        if (wv != 0.0f) {
            int xi = (int)fminf(fmaxf(xc, 0.0f), 255.0f);
            int yi = (int)fminf(fmaxf(yc, 0.0f), 255.0f);
            int ii = yi * WW + xi;
            atomicAdd(ab + ii, fmul_sr(nR, wv));
            atomicAdd(wb + ii, wv);
        }
    }
}

__global__ void k_finlast(float* __restrict__ out, float* __restrict__ wacc) {
    int idx = blockIdx.x * blockDim.x + threadIdx.x;
    if (idx >= NPT) return;
    do_fin(out, wacc + (size_t)((TT - 1) & 1) * NPT, idx, TT - 1);
}

extern "C" void kernel_launch(void* const* d_in, const int* in_sizes, int n_in,
                              void* d_out, int out_size, void* d_ws, size_t ws_size,
                              hipStream_t stream) {
    const float* x   = (const float*)d_in[0];
    const float* dec = (const float*)d_in[1];
    float* out = (float*)d_out;

    float4* st   = (float4*)d_ws;                 // 8 MB
    float*  wacc = (float*)(st + (size_t)NPT);    // 4 MB (2 bufs) -> 12 MB total

    k_init<<<(NOUT + 255) / 256, 256, 0, stream>>>(x, out, st, wacc);
    for (int t = 0; t < TT; ++t) {
        k_fused<<<(NPT + 255) / 256, 256, 0, stream>>>(dec, out, st, wacc, t);
    }
    k_finlast<<<(NPT + 255) / 256, 256, 0, stream>>>(out, wacc);
}

// Round 18
// 2061.672 us; speedup vs baseline: 1.9696x; 1.0093x over previous
//
#include <hip/hip_runtime.h>

#define BB 8
#define TT 16
#define HH 256
#define WW 256
#define HW (HH*WW)            // 65536
#define NPT (BB*HW)           // 524288 points
#define NOUT (BB*TT*HW)       // 8388608 output elems
#define EMPTY_FLOOR 0.012f

// ws layout: state float4[NPT] = 8 MB | wacc[2][NPT] = 4 MB | acc[2][NPT] = 4 MB
// = 16 MB total (ws_size >= 20 MB proven usable in R1).
// Arithmetic VERBATIM R15 (A-init f32 bits; f64 step math, f32 state rounding;
// R6-f32 defused splat; empty-cell floor). DO NOT TOUCH.
// New in R18: (1) XCD-locality swizzle — batch = blockIdx & 7, so with
// round-robin block->XCD dispatch each XCD's L2 caches ONE batch's 6 MB dec
// slice instead of all 48 MB; (2) 2 points/thread for 2x memory-level
// parallelism on the scattered gather; (3) acc in ws dbuf -> no out zeroing.

__device__ __forceinline__ float fmul_sr(float a, float b) {
    float r = a * b;
    __asm__("" : "+v"(r));
    return r;
}

__global__ void k_init(const float* __restrict__ x, float4* __restrict__ st,
                       float* __restrict__ accw) {
    int idx = blockIdx.x * blockDim.x + threadIdx.x;   // 0..NPT-1
    if (idx >= NPT) return;
    // zero both acc bufs + both wacc bufs (4*NPT floats)
    #pragma unroll
    for (int q = 0; q < 4; ++q) accw[(size_t)q * NPT + idx] = 0.0f;
    int b  = idx >> 16;
    int p  = idx & (HW - 1);
    int px = p & (WW - 1);
    int py = p >> 8;
    float4 s;
    s.x = (float)px * (1.0f / 255.0f);   // A-init bits (proven basin)
    s.y = (float)py * (1.0f / 255.0f);
    s.z = x[(size_t)(b * TT + (TT - 1)) * HW + p];
    s.w = 0.0f;
    st[idx] = s;
}

__device__ __forceinline__ void do_fin(float* __restrict__ out,
                                       float* __restrict__ acb,
                                       float* __restrict__ wab,
                                       int idx, int t) {
    int b = idx >> 16;
    int p = idx & (HW - 1);
    float a = acb[idx];
    float wsum = wab[idx];
    out[(size_t)(b * TT + t) * HW + p] =
        (wsum == 0.0f) ? EMPTY_FLOOR : a / fmaxf(wsum, 1e-8f);
    acb[idx] = 0.0f;
    wab[idx] = 0.0f;
}

__device__ __forceinline__ void do_point(const float* __restrict__ dec,
                                         float4* __restrict__ st,
                                         float* __restrict__ acb,
                                         float* __restrict__ wab,
                                         int idx, int t) {
    int b = idx >> 16;
    const float* U = dec + (size_t)((b * TT + t) * 3) * HW;
    const float* V = U + HW;
    const float* C = U + 2 * HW;

    float4 s = st[idx];

    // ---- R15-verbatim: f64 gather/update from f32 state ----
    double X = (double)s.x, Y = (double)s.y, R = (double)s.z;
    double ix = X * 256.0 - 0.5;
    double iy = Y * 256.0 - 0.5;
    double x0 = floor(ix);
    double y0 = floor(iy);

    double gU = 0.0, gV = 0.0, gC = 0.0;
    #pragma unroll
    for (int k = 0; k < 4; ++k) {
        double dxf = (double)(k & 1), dyf = (double)(k >> 1);
        double xc = x0 + dxf, yc = y0 + dyf;
        double w = (1.0 - fabs(ix - xc)) * (1.0 - fabs(iy - yc));
        bool valid = (xc >= 0.0) && (xc < 256.0) && (yc >= 0.0) && (yc < 256.0);
        double wv = valid ? w : 0.0;
        int xi = (int)fmin(fmax(xc, 0.0), 255.0);
        int yi = (int)fmin(fmax(yc, 0.0), 255.0);
        int ii = yi * WW + xi;
        double uT = (((double)U[ii] - 0.5) * 5.0) / 256.0;
        double vT = (((double)V[ii] - 0.5) * 5.0) / 256.0;
        double cT = (double)C[ii];
        gU = gU + uT * wv;
        gV = gV + vT * wv;
        gC = gC + cT * wv;
    }

    double nXd = X + gU; nXd = fmin(fmax(nXd, 0.0), 1.0);
    double nYd = Y + gV; nYd = fmin(fmax(nYd, 0.0), 1.0);
    double nRd = R * gC; nRd = fmin(fmax(nRd, 0.0), 1.0);
    float nX = (float)nXd;
    float nY = (float)nYd;
    float nR = (float)nRd;
    s.x = nX; s.y = nY; s.z = nR;
    st[idx] = s;

    // ---- R15-verbatim splat (f32, defused) ----
    float sx = fmul_sr(nX, 255.0f);
    float sy = fmul_sr(nY, 255.0f);
    float sx0 = floorf(sx);
    float sy0 = floorf(sy);

    float* ab = acb + (size_t)b * HW;
    float* wb = wab + (size_t)b * HW;

    #pragma unroll
    for (int k = 0; k < 4; ++k) {
        float dxf = (float)(k & 1), dyf = (float)(k >> 1);
        float xc = sx0 + dxf, yc = sy0 + dyf;
        float w = fmul_sr(1.0f - fabsf(sx - xc), 1.0f - fabsf(sy - yc));
        bool valid = (xc >= 0.0f) && (xc <= 255.0f) && (yc >= 0.0f) && (yc <= 255.0f);
        float wv = valid ? w : 0.0f;
        if (wv != 0.0f) {
            int xi = (int)fminf(fmaxf(xc, 0.0f), 255.0f);
            int yi = (int)fminf(fmaxf(yc, 0.0f), 255.0f);
            int ii = yi * WW + xi;
            atomicAdd(ab + ii, fmul_sr(nR, wv));
            atomicAdd(wb + ii, wv);
        }
    }
}

// grid: 1024 blocks x 256. batch = blockIdx&7 (XCD-locality swizzle);
// each thread handles points {batch*HW + sub*512 + tid, +256}.
__global__ void k_fused(const float* __restrict__ dec, float* __restrict__ out,
                        float4* __restrict__ st, float* __restrict__ acc,
                        float* __restrict__ wacc, int t) {
#pragma clang fp contract(off)
    int b   = blockIdx.x & 7;
    int sub = blockIdx.x >> 3;                 // 0..127
    int p0  = (b << 16) + sub * 512 + threadIdx.x;
    int idx0 = p0, idx1 = p0 + 256;

    float* acb_prev = acc  + (size_t)((t + 1) & 1) * NPT;
    float* wab_prev = wacc + (size_t)((t + 1) & 1) * NPT;
    float* acb = acc  + (size_t)(t & 1) * NPT;
    float* wab = wacc + (size_t)(t & 1) * NPT;

    if (t > 0) {
        do_fin(out, acb_prev, wab_prev, idx0, t - 1);
        do_fin(out, acb_prev, wab_prev, idx1, t - 1);
    }
    do_point(dec, st, acb, wab, idx0, t);
    do_point(dec, st, acb, wab, idx1, t);
}

__global__ void k_finlast(float* __restrict__ out, float* __restrict__ acc,
                          float* __restrict__ wacc) {
    int b   = blockIdx.x & 7;
    int sub = blockIdx.x >> 3;
    int p0  = (b << 16) + sub * 512 + threadIdx.x;
    float* acb = acc  + (size_t)((TT - 1) & 1) * NPT;
    float* wab = wacc + (size_t)((TT - 1) & 1) * NPT;
    do_fin(out, acb, wab, p0, TT - 1);
    do_fin(out, acb, wab, p0 + 256, TT - 1);
}

extern "C" void kernel_launch(void* const* d_in, const int* in_sizes, int n_in,
                              void* d_out, int out_size, void* d_ws, size_t ws_size,
                              hipStream_t stream) {
    const float* x   = (const float*)d_in[0];
    const float* dec = (const float*)d_in[1];
    float* out = (float*)d_out;

    float4* st   = (float4*)d_ws;                       // 8 MB
    float*  wacc = (float*)(st + (size_t)NPT);          // 4 MB (2 bufs)
    float*  acc  = wacc + 2 * (size_t)NPT;              // 4 MB (2 bufs) -> 16 MB

    k_init<<<(NPT + 255) / 256, 256, 0, stream>>>(x, st, wacc);  // zeros wacc+acc (adjacent)
    for (int t = 0; t < TT; ++t) {
        k_fused<<<1024, 256, 0, stream>>>(dec, out, st, acc, wacc, t);
    }
    k_finlast<<<1024, 256, 0, stream>>>(out, acc, wacc);
}

// Round 19
// 2060.491 us; speedup vs baseline: 1.9708x; 1.0006x over previous
//
#include <hip/hip_runtime.h>

#define BB 8
#define TT 16
#define HH 256
#define WW 256
#define HW (HH*WW)            // 65536
#define NPT (BB*HW)           // 524288 points
#define NOUT (BB*TT*HW)       // 8388608 output elems
#define EMPTY_FLOOR 0.012f

// ws layout: state float4[NPT] = 8 MB | wacc[2][NPT] = 4 MB | acc[2][NPT] = 4 MB.
// Arithmetic VERBATIM R15/R18. DO NOT TOUCH.
// R19: splat atomics at WORKGROUP scope. Sound because (proven by R18's
// FETCH drop) blocks with equal blockIdx&7 share an XCD, and every
// contributor/reader/rezeroer of a given accumulator cell has the same
// blockIdx&7 = batch. Workgroup-scope fadd executes in the XCD-local L2
// (shared by all CUs there), avoiding the memory-side atomic path that
// capped R15-R18 at ~28.7 G atomics/s. Cross-dispatch visibility (fin at
// t+1 reading step-t sums) is ordered by kernel-boundary release/acquire.

__device__ __forceinline__ float fmul_sr(float a, float b) {
    float r = a * b;
    __asm__("" : "+v"(r));
    return r;
}

__device__ __forceinline__ void atom_add_wg(float* p, float v) {
    __hip_atomic_fetch_add(p, v, __ATOMIC_RELAXED, __HIP_MEMORY_SCOPE_WORKGROUP);
}

__global__ void k_init(const float* __restrict__ x, float4* __restrict__ st,
                       float* __restrict__ accw) {
    int idx = blockIdx.x * blockDim.x + threadIdx.x;   // 0..NPT-1
    if (idx >= NPT) return;
    #pragma unroll
    for (int q = 0; q < 4; ++q) accw[(size_t)q * NPT + idx] = 0.0f;
    int b  = idx >> 16;
    int p  = idx & (HW - 1);
    int px = p & (WW - 1);
    int py = p >> 8;
    float4 s;
    s.x = (float)px * (1.0f / 255.0f);   // A-init bits (proven basin)
    s.y = (float)py * (1.0f / 255.0f);
    s.z = x[(size_t)(b * TT + (TT - 1)) * HW + p];
    s.w = 0.0f;
    st[idx] = s;
}

__device__ __forceinline__ void do_fin(float* __restrict__ out,
                                       float* __restrict__ acb,
                                       float* __restrict__ wab,
                                       int idx, int t) {
    int b = idx >> 16;
    int p = idx & (HW - 1);
    float a = acb[idx];
    float wsum = wab[idx];
    out[(size_t)(b * TT + t) * HW + p] =
        (wsum == 0.0f) ? EMPTY_FLOOR : a / fmaxf(wsum, 1e-8f);
    acb[idx] = 0.0f;
    wab[idx] = 0.0f;
}

__device__ __forceinline__ void do_point(const float* __restrict__ dec,
                                         float4* __restrict__ st,
                                         float* __restrict__ acb,
                                         float* __restrict__ wab,
                                         int idx, int t) {
    int b = idx >> 16;
    const float* U = dec + (size_t)((b * TT + t) * 3) * HW;
    const float* V = U + HW;
    const float* C = U + 2 * HW;

    float4 s = st[idx];

    // ---- R15-verbatim: f64 gather/update from f32 state ----
    double X = (double)s.x, Y = (double)s.y, R = (double)s.z;
    double ix = X * 256.0 - 0.5;
    double iy = Y * 256.0 - 0.5;
    double x0 = floor(ix);
    double y0 = floor(iy);

    double gU = 0.0, gV = 0.0, gC = 0.0;
    #pragma unroll
    for (int k = 0; k < 4; ++k) {
        double dxf = (double)(k & 1), dyf = (double)(k >> 1);
        double xc = x0 + dxf, yc = y0 + dyf;
        double w = (1.0 - fabs(ix - xc)) * (1.0 - fabs(iy - yc));
        bool valid = (xc >= 0.0) && (xc < 256.0) && (yc >= 0.0) && (yc < 256.0);
        double wv = valid ? w : 0.0;
        int xi = (int)fmin(fmax(xc, 0.0), 255.0);
        int yi = (int)fmin(fmax(yc, 0.0), 255.0);
        int ii = yi * WW + xi;
        double uT = (((double)U[ii] - 0.5) * 5.0) / 256.0;
        double vT = (((double)V[ii] - 0.5) * 5.0) / 256.0;
        double cT = (double)C[ii];
        gU = gU + uT * wv;
        gV = gV + vT * wv;
        gC = gC + cT * wv;
    }

    double nXd = X + gU; nXd = fmin(fmax(nXd, 0.0), 1.0);
    double nYd = Y + gV; nYd = fmin(fmax(nYd, 0.0), 1.0);
    double nRd = R * gC; nRd = fmin(fmax(nRd, 0.0), 1.0);
    float nX = (float)nXd;
    float nY = (float)nYd;
    float nR = (float)nRd;
    s.x = nX; s.y = nY; s.z = nR;
    st[idx] = s;

    // ---- R15-verbatim splat (f32, defused); workgroup-scope atomics ----
    float sx = fmul_sr(nX, 255.0f);
    float sy = fmul_sr(nY, 255.0f);
    float sx0 = floorf(sx);
    float sy0 = floorf(sy);

    float* ab = acb + (size_t)b * HW;
    float* wb = wab + (size_t)b * HW;

    #pragma unroll
    for (int k = 0; k < 4; ++k) {
        float dxf = (float)(k & 1), dyf = (float)(k >> 1);
        float xc = sx0 + dxf, yc = sy0 + dyf;
        float w = fmul_sr(1.0f - fabsf(sx - xc), 1.0f - fabsf(sy - yc));
        bool valid = (xc >= 0.0f) && (xc <= 255.0f) && (yc >= 0.0f) && (yc <= 255.0f);
        float wv = valid ? w : 0.0f;
        if (wv != 0.0f) {
            int xi = (int)fminf(fmaxf(xc, 0.0f), 255.0f);
            int yi = (int)fminf(fmaxf(yc, 0.0f), 255.0f);
            int ii = yi * WW + xi;
            atom_add_wg(ab + ii, fmul_sr(nR, wv));
            atom_add_wg(wb + ii, wv);
        }
    }
}

// grid: 1024 blocks x 256. batch = blockIdx&7 (XCD-locality swizzle).
__global__ void k_fused(const float* __restrict__ dec, float* __restrict__ out,
                        float4* __restrict__ st, float* __restrict__ acc,
                        float* __restrict__ wacc, int t) {
#pragma clang fp contract(off)
    int b   = blockIdx.x & 7;
    int sub = blockIdx.x >> 3;                 // 0..127
    int p0  = (b << 16) + sub * 512 + threadIdx.x;
    int idx0 = p0, idx1 = p0 + 256;

    float* acb_prev = acc  + (size_t)((t + 1) & 1) * NPT;
    float* wab_prev = wacc + (size_t)((t + 1) & 1) * NPT;
    float* acb = acc  + (size_t)(t & 1) * NPT;
    float* wab = wacc + (size_t)(t & 1) * NPT;

    if (t > 0) {
        do_fin(out, acb_prev, wab_prev, idx0, t - 1);
        do_fin(out, acb_prev, wab_prev, idx1, t - 1);
    }
    do_point(dec, st, acb, wab, idx0, t);
    do_point(dec, st, acb, wab, idx1, t);
}

__global__ void k_finlast(float* __restrict__ out, float* __restrict__ acc,
                          float* __restrict__ wacc) {
    int b   = blockIdx.x & 7;
    int sub = blockIdx.x >> 3;
    int p0  = (b << 16) + sub * 512 + threadIdx.x;
    float* acb = acc  + (size_t)((TT - 1) & 1) * NPT;
    float* wab = wacc + (size_t)((TT - 1) & 1) * NPT;
    do_fin(out, acb, wab, p0, TT - 1);
    do_fin(out, acb, wab, p0 + 256, TT - 1);
}

extern "C" void kernel_launch(void* const* d_in, const int* in_sizes, int n_in,
                              void* d_out, int out_size, void* d_ws, size_t ws_size,
                              hipStream_t stream) {
    const float* x   = (const float*)d_in[0];
    const float* dec = (const float*)d_in[1];
    float* out = (float*)d_out;

    float4* st   = (float4*)d_ws;                       // 8 MB
    float*  wacc = (float*)(st + (size_t)NPT);          // 4 MB (2 bufs)
    float*  acc  = wacc + 2 * (size_t)NPT;              // 4 MB (2 bufs) -> 16 MB

    k_init<<<(NPT + 255) / 256, 256, 0, stream>>>(x, st, wacc);
    for (int t = 0; t < TT; ++t) {
        k_fused<<<1024, 256, 0, stream>>>(dec, out, st, acc, wacc, t);
    }
    k_finlast<<<1024, 256, 0, stream>>>(out, acc, wacc);
}

// Round 20
// 1545.497 us; speedup vs baseline: 2.6275x; 1.3332x over previous
//
#include <hip/hip_runtime.h>

#define BB 8
#define TT 16
#define HH 256
#define WW 256
#define HW (HH*WW)            // 65536
#define NPT (BB*HW)           // 524288 points
#define NBIN 65536            // bins per batch (256x256 of (sy0,sx0))
#define EMPTY_FLOOR 0.012f

// ws: st float4[NPT]=8MB | rec Rec[NPT]=6MB | hist u32[NPT]=2MB |
//     off u32[NPT]=2MB | cursor u32[NPT]=2MB   => 20 MB exactly (R1-proven).
// Arithmetic VERBATIM R15 (A-init f32 bits; f64 step math, f32 state rounding;
// R6-f32 defused splat weights; empty-cell floor 0.012). DO NOT TOUCH.
// R20: splat-by-atomics replaced by bin+gather: histogram -> scan -> scatter
// records -> per-tile LDS gather. No global f32 atomics anywhere.

struct Rec { float sx, sy, nR; };

__device__ __forceinline__ float fmul_sr(float a, float b) {
    float r = a * b;
    __asm__("" : "+v"(r));
    return r;
}

__global__ void k_init(const float* __restrict__ x, float4* __restrict__ st,
                       unsigned* __restrict__ hist) {
    int idx = blockIdx.x * blockDim.x + threadIdx.x;
    if (idx >= NPT) return;
    hist[idx] = 0u;
    int b  = idx >> 16;
    int p  = idx & (HW - 1);
    int px = p & (WW - 1);
    int py = p >> 8;
    float4 s;
    s.x = (float)px * (1.0f / 255.0f);   // A-init bits (proven basin)
    s.y = (float)py * (1.0f / 255.0f);
    s.z = x[(size_t)(b * TT + (TT - 1)) * HW + p];
    s.w = 0.0f;
    st[idx] = s;
}

// ---- R15-verbatim advection for one point; also histogram its splat bin ----
__device__ __forceinline__ void adv_point(const float* __restrict__ dec,
                                          float4* __restrict__ st,
                                          unsigned* __restrict__ hist,
                                          int idx, int t) {
    int b = idx >> 16;
    const float* U = dec + (size_t)((b * TT + t) * 3) * HW;
    const float* V = U + HW;
    const float* C = U + 2 * HW;

    float4 s = st[idx];
    double X = (double)s.x, Y = (double)s.y, R = (double)s.z;
    double ix = X * 256.0 - 0.5;
    double iy = Y * 256.0 - 0.5;
    double x0 = floor(ix);
    double y0 = floor(iy);

    double gU = 0.0, gV = 0.0, gC = 0.0;
    #pragma unroll
    for (int k = 0; k < 4; ++k) {
        double dxf = (double)(k & 1), dyf = (double)(k >> 1);
        double xc = x0 + dxf, yc = y0 + dyf;
        double w = (1.0 - fabs(ix - xc)) * (1.0 - fabs(iy - yc));
        bool valid = (xc >= 0.0) && (xc < 256.0) && (yc >= 0.0) && (yc < 256.0);
        double wv = valid ? w : 0.0;
        int xi = (int)fmin(fmax(xc, 0.0), 255.0);
        int yi = (int)fmin(fmax(yc, 0.0), 255.0);
        int ii = yi * WW + xi;
        double uT = (((double)U[ii] - 0.5) * 5.0) / 256.0;
        double vT = (((double)V[ii] - 0.5) * 5.0) / 256.0;
        double cT = (double)C[ii];
        gU = gU + uT * wv;
        gV = gV + vT * wv;
        gC = gC + cT * wv;
    }

    double nXd = X + gU; nXd = fmin(fmax(nXd, 0.0), 1.0);
    double nYd = Y + gV; nYd = fmin(fmax(nYd, 0.0), 1.0);
    double nRd = R * gC; nRd = fmin(fmax(nRd, 0.0), 1.0);
    float nX = (float)nXd;
    float nY = (float)nYd;
    float nR = (float)nRd;
    s.x = nX; s.y = nY; s.z = nR;
    st[idx] = s;

    float sx = fmul_sr(nX, 255.0f);
    float sy = fmul_sr(nY, 255.0f);
    int bin = ((int)floorf(sy)) * 256 + (int)floorf(sx);   // in [0,65535]
    atomicAdd(&hist[(b << 16) + bin], 1u);
}

__global__ void k_adv(const float* __restrict__ dec, float4* __restrict__ st,
                      unsigned* __restrict__ hist, int t) {
#pragma clang fp contract(off)
    int b   = blockIdx.x & 7;
    int sub = blockIdx.x >> 3;
    int p0  = (b << 16) + sub * 512 + threadIdx.x;
    adv_point(dec, st, hist, p0, t);
    adv_point(dec, st, hist, p0 + 256, t);
}

// one block (1024 thr) per batch: exclusive scan of 65536 bins; rezero hist
__global__ __launch_bounds__(1024) void k_scan(unsigned* __restrict__ hist,
                                               unsigned* __restrict__ off,
                                               unsigned* __restrict__ cursor) {
    int b   = blockIdx.x & 7;
    int tid = threadIdx.x;
    unsigned* h = hist   + (b << 16);
    unsigned* o = off    + (b << 16);
    unsigned* c = cursor + (b << 16);
    int base = tid * 64;

    unsigned tot = 0;
    for (int i = 0; i < 64; ++i) tot += h[base + i];

    __shared__ unsigned ls[1024];
    ls[tid] = tot;
    __syncthreads();
    for (int ofs = 1; ofs < 1024; ofs <<= 1) {
        unsigned v = (tid >= ofs) ? ls[tid - ofs] : 0u;
        __syncthreads();
        ls[tid] += v;
        __syncthreads();
    }
    unsigned run = ls[tid] - tot;   // exclusive base for this chunk

    for (int i = 0; i < 64; ++i) {
        unsigned v = h[base + i];
        o[base + i] = run;
        c[base + i] = run;
        h[base + i] = 0u;
        run += v;
    }
}

__global__ void k_scat(const float4* __restrict__ st, Rec* __restrict__ rec,
                       unsigned* __restrict__ cursor) {
    int b   = blockIdx.x & 7;
    int sub = blockIdx.x >> 3;
    int p0  = (b << 16) + sub * 512 + threadIdx.x;
    #pragma unroll
    for (int q = 0; q < 2; ++q) {
        int idx = p0 + q * 256;
        float4 s = st[idx];
        float sx = fmul_sr(s.x, 255.0f);   // same bits as k_adv's
        float sy = fmul_sr(s.y, 255.0f);
        int bin = ((int)floorf(sy)) * 256 + (int)floorf(sx);
        unsigned slot = atomicAdd(&cursor[(b << 16) + bin], 1u);
        Rec r; r.sx = sx; r.sy = sy; r.nR = s.z;
        rec[((size_t)b << 16) + slot] = r;
    }
}

// per-tile gather (32x16 cells) + fused advection of step t+1
__global__ __launch_bounds__(256) void k_gathadv(
        const Rec* __restrict__ rec, const unsigned* __restrict__ off,
        float* __restrict__ out, const float* __restrict__ dec,
        float4* __restrict__ st, unsigned* __restrict__ hist, int t) {
#pragma clang fp contract(off)
    int b    = blockIdx.x & 7;
    int tile = blockIdx.x >> 3;          // 0..127
    int x0 = (tile & 7) * 32;
    int y0 = (tile >> 3) * 16;
    int tid = threadIdx.x;

    __shared__ float a_lds[16][32];
    __shared__ float w_lds[16][32];
    a_lds[tid >> 5][tid & 31] = 0.0f;
    w_lds[tid >> 5][tid & 31] = 0.0f;
    a_lds[(tid >> 5) + 8][tid & 31] = 0.0f;
    w_lds[(tid >> 5) + 8][tid & 31] = 0.0f;
    __syncthreads();

    const unsigned* ob = off + (b << 16);
    const Rec*      rb = rec + ((size_t)b << 16);
    int wave = tid >> 6, lane = tid & 63;

    for (int r = wave; r < 17; r += 4) {
        int by = y0 - 1 + r;
        if (by < 0) continue;            // by <= y0+15 <= 255 always
        int bx0 = (x0 == 0) ? 0 : x0 - 1;
        int bx1 = x0 + 31;               // <= 255
        unsigned sbeg = ob[by * 256 + bx0];
        int ebin = by * 256 + bx1;
        unsigned send = (ebin == 65535) ? (unsigned)HW : ob[ebin + 1];
        for (unsigned i = sbeg + lane; i < send; i += 64) {
            Rec rr = rb[i];
            float sx0f = floorf(rr.sx), sy0f = floorf(rr.sy);
            #pragma unroll
            for (int k = 0; k < 4; ++k) {
                float dxf = (float)(k & 1), dyf = (float)(k >> 1);
                float xc = sx0f + dxf, yc = sy0f + dyf;   // exact
                int cxi = (int)xc, cy = (int)yc;
                if (cxi >= x0 && cxi < x0 + 32 && cy >= y0 && cy < y0 + 16) {
                    float w = fmul_sr(1.0f - fabsf(rr.sx - xc),
                                      1.0f - fabsf(rr.sy - yc));
                    if (w != 0.0f) {                      // matches splat skip
                        atomicAdd(&a_lds[cy - y0][cxi - x0], fmul_sr(rr.nR, w));
                        atomicAdd(&w_lds[cy - y0][cxi - x0], w);
                    }
                }
            }
        }
    }
    __syncthreads();

    size_t obase = (size_t)(b * TT + t) * HW;
    #pragma unroll
    for (int q = 0; q < 2; ++q) {
        int c = tid + q * 256;
        int row = c >> 5, col = c & 31;
        float a = a_lds[row][col];
        float w = w_lds[row][col];
        out[obase + (size_t)(y0 + row) * 256 + x0 + col] =
            (w == 0.0f) ? EMPTY_FLOOR : a / fmaxf(w, 1e-8f);
    }

    // ---- fused advection of step t+1 (independent of gather above) ----
    int tA = t + 1;
    if (tA < TT) {
        int sub = blockIdx.x >> 3;
        int p0  = (b << 16) + sub * 512 + tid;
        adv_point(dec, st, hist, p0, tA);
        adv_point(dec, st, hist, p0 + 256, tA);
    }
}

extern "C" void kernel_launch(void* const* d_in, const int* in_sizes, int n_in,
                              void* d_out, int out_size, void* d_ws, size_t ws_size,
                              hipStream_t stream) {
    const float* x   = (const float*)d_in[0];
    const float* dec = (const float*)d_in[1];
    float* out = (float*)d_out;

    float4*   st     = (float4*)d_ws;                                   // 8 MB
    Rec*      rec    = (Rec*)(st + (size_t)NPT);                        // 6 MB
    unsigned* hist   = (unsigned*)((char*)rec + (size_t)NPT * sizeof(Rec)); // 2 MB
    unsigned* off    = hist + (size_t)NPT;                              // 2 MB
    unsigned* cursor = off + (size_t)NPT;                               // 2 MB = 20 MB

    k_init<<<(NPT + 255) / 256, 256, 0, stream>>>(x, st, hist);
    k_adv<<<1024, 256, 0, stream>>>(dec, st, hist, 0);
    for (int t = 0; t < TT; ++t) {
        k_scan<<<8, 1024, 0, stream>>>(hist, off, cursor);
        k_scat<<<1024, 256, 0, stream>>>(st, rec, cursor);
        k_gathadv<<<1024, 256, 0, stream>>>(rec, off, out, dec, st, hist, t);
    }
}

// Round 21
// 914.484 us; speedup vs baseline: 4.4405x; 1.6900x over previous
//
#include <hip/hip_runtime.h>

#define BB 8
#define TT 16
#define HH 256
#define WW 256
#define HW (HH*WW)            // 65536
#define NPT (BB*HW)           // 524288 points
#define EMPTY_FLOOR 0.012f

// ws: st float4[NPT]=8MB | rec Rec[NPT]=6MB | hist u32[NPT]=2MB |
//     off u32[NPT]=2MB | cursor u32[NPT]=2MB => 20 MB exactly (proven).
// rowtot lives in a 8KB __device__ array (no ws growth).
// Arithmetic VERBATIM R15 (A-init f32 bits; f64 step math, f32 state rounding;
// R6-f32 defused splat weights; empty-cell floor 0.012). DO NOT TOUCH.
// R21: k_scan parallelized 8 -> 2048 blocks (two-level scan: per-row local
// offsets + rowtot; consumers re-derive row bases with a 256-wide LDS scan).

struct Rec { float sx, sy, nR; };

__device__ unsigned g_rowtot[BB][HH];   // 8 KB

__device__ __forceinline__ float fmul_sr(float a, float b) {
    float r = a * b;
    __asm__("" : "+v"(r));
    return r;
}

__global__ void k_init(const float* __restrict__ x, float4* __restrict__ st,
                       unsigned* __restrict__ hist) {
    int idx = blockIdx.x * blockDim.x + threadIdx.x;
    if (idx >= NPT) return;
    hist[idx] = 0u;
    int b  = idx >> 16;
    int p  = idx & (HW - 1);
    int px = p & (WW - 1);
    int py = p >> 8;
    float4 s;
    s.x = (float)px * (1.0f / 255.0f);   // A-init bits (proven basin)
    s.y = (float)py * (1.0f / 255.0f);
    s.z = x[(size_t)(b * TT + (TT - 1)) * HW + p];
    s.w = 0.0f;
    st[idx] = s;
}

// ---- R15-verbatim advection for one point; histogram its splat bin ----
__device__ __forceinline__ void adv_point(const float* __restrict__ dec,
                                          float4* __restrict__ st,
                                          unsigned* __restrict__ hist,
                                          int idx, int t) {
    int b = idx >> 16;
    const float* U = dec + (size_t)((b * TT + t) * 3) * HW;
    const float* V = U + HW;
    const float* C = U + 2 * HW;

    float4 s = st[idx];
    double X = (double)s.x, Y = (double)s.y, R = (double)s.z;
    double ix = X * 256.0 - 0.5;
    double iy = Y * 256.0 - 0.5;
    double x0 = floor(ix);
    double y0 = floor(iy);

    double gU = 0.0, gV = 0.0, gC = 0.0;
    #pragma unroll
    for (int k = 0; k < 4; ++k) {
        double dxf = (double)(k & 1), dyf = (double)(k >> 1);
        double xc = x0 + dxf, yc = y0 + dyf;
        double w = (1.0 - fabs(ix - xc)) * (1.0 - fabs(iy - yc));
        bool valid = (xc >= 0.0) && (xc < 256.0) && (yc >= 0.0) && (yc < 256.0);
        double wv = valid ? w : 0.0;
        int xi = (int)fmin(fmax(xc, 0.0), 255.0);
        int yi = (int)fmin(fmax(yc, 0.0), 255.0);
        int ii = yi * WW + xi;
        double uT = (((double)U[ii] - 0.5) * 5.0) / 256.0;
        double vT = (((double)V[ii] - 0.5) * 5.0) / 256.0;
        double cT = (double)C[ii];
        gU = gU + uT * wv;
        gV = gV + vT * wv;
        gC = gC + cT * wv;
    }

    double nXd = X + gU; nXd = fmin(fmax(nXd, 0.0), 1.0);
    double nYd = Y + gV; nYd = fmin(fmax(nYd, 0.0), 1.0);
    double nRd = R * gC; nRd = fmin(fmax(nRd, 0.0), 1.0);
    float nX = (float)nXd;
    float nY = (float)nYd;
    float nR = (float)nRd;
    s.x = nX; s.y = nY; s.z = nR;
    st[idx] = s;

    float sx = fmul_sr(nX, 255.0f);
    float sy = fmul_sr(nY, 255.0f);
    int bin = ((int)floorf(sy)) * 256 + (int)floorf(sx);
    atomicAdd(&hist[(b << 16) + bin], 1u);
}

__global__ void k_adv(const float* __restrict__ dec, float4* __restrict__ st,
                      unsigned* __restrict__ hist, int t) {
#pragma clang fp contract(off)
    int b   = blockIdx.x & 7;
    int sub = blockIdx.x >> 3;
    int p0  = (b << 16) + sub * 512 + threadIdx.x;
    adv_point(dec, st, hist, p0, t);
    adv_point(dec, st, hist, p0 + 256, t);
}

// 2048 blocks (8 batches x 256 rows), 256 thr: per-row local exclusive scan.
__global__ __launch_bounds__(256) void k_scan(unsigned* __restrict__ hist,
                                              unsigned* __restrict__ off,
                                              unsigned* __restrict__ cursor) {
    int b   = blockIdx.x & 7;
    int row = blockIdx.x >> 3;
    int tid = threadIdx.x;
    int bin = (b << 16) + row * 256 + tid;

    unsigned v = hist[bin];
    __shared__ unsigned ls[256];
    ls[tid] = v;
    __syncthreads();
    #pragma unroll
    for (int ofs = 1; ofs < 256; ofs <<= 1) {
        unsigned u = (tid >= ofs) ? ls[tid - ofs] : 0u;
        __syncthreads();
        ls[tid] += u;
        __syncthreads();
    }
    unsigned excl = ls[tid] - v;
    off[bin]    = excl;
    cursor[bin] = excl;
    hist[bin]   = 0u;
    if (tid == 255) g_rowtot[b][row] = ls[255];
}

// LDS helper: exclusive row-base scan of g_rowtot[b][*] into rbase[256];
// also copies row totals into rtot[256].
__device__ __forceinline__ void load_rowbases(int b, unsigned* rbase,
                                              unsigned* rtot) {
    int tid = threadIdx.x;
    unsigned v = g_rowtot[b][tid];
    rtot[tid]  = v;
    rbase[tid] = v;
    __syncthreads();
    #pragma unroll
    for (int ofs = 1; ofs < 256; ofs <<= 1) {
        unsigned u = (tid >= ofs) ? rbase[tid - ofs] : 0u;
        __syncthreads();
        rbase[tid] += u;
        __syncthreads();
    }
    rbase[tid] -= v;     // exclusive
    __syncthreads();
}

__global__ __launch_bounds__(256) void k_scat(const float4* __restrict__ st,
                                              Rec* __restrict__ rec,
                                              unsigned* __restrict__ cursor) {
#pragma clang fp contract(off)
    __shared__ unsigned rbase[256];
    __shared__ unsigned rtot[256];
    int b   = blockIdx.x & 7;
    int sub = blockIdx.x >> 3;
    load_rowbases(b, rbase, rtot);

    int p0 = (b << 16) + sub * 512 + threadIdx.x;
    #pragma unroll
    for (int q = 0; q < 2; ++q) {
        int idx = p0 + q * 256;
        float4 s = st[idx];
        float sx = fmul_sr(s.x, 255.0f);   // same bits as adv's
        float sy = fmul_sr(s.y, 255.0f);
        int row = (int)floorf(sy);
        int bin = row * 256 + (int)floorf(sx);
        unsigned slot = rbase[row] + atomicAdd(&cursor[(b << 16) + bin], 1u);
        Rec r; r.sx = sx; r.sy = sy; r.nR = s.z;
        rec[((size_t)b << 16) + slot] = r;
    }
}

// per-tile gather (32x16 cells) + fused advection of step t+1
__global__ __launch_bounds__(256) void k_gathadv(
        const Rec* __restrict__ rec, const unsigned* __restrict__ off,
        float* __restrict__ out, const float* __restrict__ dec,
        float4* __restrict__ st, unsigned* __restrict__ hist, int t) {
#pragma clang fp contract(off)
    __shared__ unsigned rbase[256];
    __shared__ unsigned rtot[256];
    __shared__ float a_lds[16][32];
    __shared__ float w_lds[16][32];

    int b    = blockIdx.x & 7;
    int tile = blockIdx.x >> 3;          // 0..127
    int x0 = (tile & 7) * 32;
    int y0 = (tile >> 3) * 16;
    int tid = threadIdx.x;

    load_rowbases(b, rbase, rtot);

    a_lds[tid >> 5][tid & 31] = 0.0f;
    w_lds[tid >> 5][tid & 31] = 0.0f;
    a_lds[(tid >> 5) + 8][tid & 31] = 0.0f;
    w_lds[(tid >> 5) + 8][tid & 31] = 0.0f;
    __syncthreads();

    const unsigned* ob = off + (b << 16);
    const Rec*      rb = rec + ((size_t)b << 16);
    int wave = tid >> 6, lane = tid & 63;

    for (int r = wave; r < 17; r += 4) {
        int by = y0 - 1 + r;
        if (by < 0) continue;            // by <= 255 always
        int bx0 = (x0 == 0) ? 0 : x0 - 1;
        int bx1 = x0 + 31;               // <= 255
        unsigned base = rbase[by];
        unsigned sbeg = base + ob[by * 256 + bx0];
        unsigned send = base + ((bx1 == 255) ? rtot[by] : ob[by * 256 + bx1 + 1]);
        for (unsigned i = sbeg + lane; i < send; i += 64) {
            Rec rr = rb[i];
            float sx0f = floorf(rr.sx), sy0f = floorf(rr.sy);
            #pragma unroll
            for (int k = 0; k < 4; ++k) {
                float dxf = (float)(k & 1), dyf = (float)(k >> 1);
                float xc = sx0f + dxf, yc = sy0f + dyf;   // exact
                int cxi = (int)xc, cy = (int)yc;
                if (cxi >= x0 && cxi < x0 + 32 && cy >= y0 && cy < y0 + 16) {
                    float w = fmul_sr(1.0f - fabsf(rr.sx - xc),
                                      1.0f - fabsf(rr.sy - yc));
                    if (w != 0.0f) {                      // matches splat skip
                        atomicAdd(&a_lds[cy - y0][cxi - x0], fmul_sr(rr.nR, w));
                        atomicAdd(&w_lds[cy - y0][cxi - x0], w);
                    }
                }
            }
        }
    }
    __syncthreads();

    size_t obase = (size_t)(b * TT + t) * HW;
    #pragma unroll
    for (int q = 0; q < 2; ++q) {
        int c = tid + q * 256;
        int row = c >> 5, col = c & 31;
        float a = a_lds[row][col];
        float w = w_lds[row][col];
        out[obase + (size_t)(y0 + row) * 256 + x0 + col] =
            (w == 0.0f) ? EMPTY_FLOOR : a / fmaxf(w, 1e-8f);
    }

    // ---- fused advection of step t+1 (independent of gather above) ----
    int tA = t + 1;
    if (tA < TT) {
        int sub = blockIdx.x >> 3;
        int p0  = (b << 16) + sub * 512 + tid;
        adv_point(dec, st, hist, p0, tA);
        adv_point(dec, st, hist, p0 + 256, tA);
    }
}

extern "C" void kernel_launch(void* const* d_in, const int* in_sizes, int n_in,
                              void* d_out, int out_size, void* d_ws, size_t ws_size,
                              hipStream_t stream) {
    const float* x   = (const float*)d_in[0];
    const float* dec = (const float*)d_in[1];
    float* out = (float*)d_out;

    float4*   st     = (float4*)d_ws;                                       // 8 MB
    Rec*      rec    = (Rec*)(st + (size_t)NPT);                            // 6 MB
    unsigned* hist   = (unsigned*)((char*)rec + (size_t)NPT * sizeof(Rec)); // 2 MB
    unsigned* off    = hist + (size_t)NPT;                                  // 2 MB
    unsigned* cursor = off + (size_t)NPT;                                   // 2 MB = 20 MB

    k_init<<<(NPT + 255) / 256, 256, 0, stream>>>(x, st, hist);
    k_adv<<<1024, 256, 0, stream>>>(dec, st, hist, 0);
    for (int t = 0; t < TT; ++t) {
        k_scan<<<2048, 256, 0, stream>>>(hist, off, cursor);
        k_scat<<<1024, 256, 0, stream>>>(st, rec, cursor);
        k_gathadv<<<1024, 256, 0, stream>>>(rec, off, out, dec, st, hist, t);
    }
}